// Round 1
// baseline (372.630 us; speedup 1.0000x reference)
//
#include <hip/hip_runtime.h>

// UpSample1d (ratio=2) as closed-form polyphase filter:
//   out[2s]   = 2*(f1*x[s+2]+f3*x[s+1]+f5*x[s]+f7*x[s-1]+f9*x[s-2]+f11*x[s-3])
//   out[2s+1] = 2*(f0*x[s+3]+f2*x[s+2]+f4*x[s+1]+f6*x[s]+f8*x[s-1]+f10*x[s-2])
// with edge-clamped x (replicate pad). Memory-bound: 128MiB in, 256MiB out.

constexpr int T_IN  = 8192;
constexpr int T_OUT = 16384;
constexpr int SPT   = 4;           // s-values per thread (8 outputs)
constexpr int JPR   = T_IN / SPT;  // 2048 work items per row
static_assert(JPR == 2048, "shift constant below assumes JPR=2048");

__global__ __launch_bounds__(256)
void upsample2x_kernel(const float* __restrict__ x,
                       const float* __restrict__ filt,
                       float* __restrict__ out,
                       long long total)
{
    // Filter taps: uniform address -> scalar loads, hoisted out of the loop.
    float f[12];
#pragma unroll
    for (int i = 0; i < 12; ++i) f[i] = filt[i];

    long long tid    = (long long)blockIdx.x * blockDim.x + threadIdx.x;
    long long stride = (long long)gridDim.x * blockDim.x;

    for (long long w = tid; w < total; w += stride) {
        int row = (int)(w >> 11);          // w / JPR
        int j   = (int)(w & (JPR - 1));    // w % JPR
        int s0  = j * SPT;

        const float* xr = x + (long long)row * T_IN;

        float xv[12];  // x[s0-4 .. s0+7]
        if (j > 0 && j < JPR - 1) {
            // Interior: three aligned float4 loads (s0-4 is a multiple of 4).
            const float4* p = (const float4*)(xr + (s0 - 4));
            float4 a = p[0], b = p[1], c = p[2];
            xv[0] = a.x; xv[1] = a.y; xv[2]  = a.z; xv[3]  = a.w;
            xv[4] = b.x; xv[5] = b.y; xv[6]  = b.z; xv[7]  = b.w;
            xv[8] = c.x; xv[9] = c.y; xv[10] = c.z; xv[11] = c.w;
        } else {
            // Row edges: clamped scalar loads (replicate padding).
#pragma unroll
            for (int i = 0; i < 12; ++i) {
                int ii = s0 - 4 + i;
                ii = ii < 0 ? 0 : (ii > T_IN - 1 ? T_IN - 1 : ii);
                xv[i] = xr[ii];
            }
        }

        float o[8];
#pragma unroll
        for (int q = 0; q < SPT; ++q) {
            int b = 4 + q;  // index of x[s] within xv
            float ev = f[1] * xv[b + 2] + f[3] * xv[b + 1] + f[5]  * xv[b + 0]
                     + f[7] * xv[b - 1] + f[9] * xv[b - 2] + f[11] * xv[b - 3];
            float od = f[0] * xv[b + 3] + f[2] * xv[b + 2] + f[4]  * xv[b + 1]
                     + f[6] * xv[b + 0] + f[8] * xv[b - 1] + f[10] * xv[b - 2];
            o[2 * q]     = 2.0f * ev;
            o[2 * q + 1] = 2.0f * od;
        }

        // Two aligned float4 stores (2*s0 is a multiple of 8 -> 32B aligned).
        float4* po = (float4*)(out + (long long)row * T_OUT + 2 * s0);
        po[0] = make_float4(o[0], o[1], o[2], o[3]);
        po[1] = make_float4(o[4], o[5], o[6], o[7]);
    }
}

extern "C" void kernel_launch(void* const* d_in, const int* in_sizes, int n_in,
                              void* d_out, int out_size, void* d_ws, size_t ws_size,
                              hipStream_t stream) {
    const float* x    = (const float*)d_in[0];
    const float* filt = (const float*)d_in[1];
    float* out        = (float*)d_out;

    long long rows  = (long long)in_sizes[0] / T_IN;   // 8*512 = 4096
    long long total = rows * JPR;                      // 8,388,608 work items

    const int block = 256;
    int grid = 2048;  // 8 blocks/CU, grid-stride (16 items/thread)
    upsample2x_kernel<<<grid, block, 0, stream>>>(x, filt, out, total);
}